// Round 12
// baseline (514.413 us; speedup 1.0000x reference)
//
#include <hip/hip_runtime.h>
#include <math.h>

// ---------------------------------------------------------------------------
// CapsNet forward on MI355X.
// R23: R22 base (caps barrier-thinned, = R19 within noise; best 486-488us)
//      + T5 s_setprio(1/0) around conv2's MFMA clusters. Mechanism: 2
//      desynced blocks/CU give wave role-diversity (one block stages while
//      the other computes) -- the regime where setprio pays (m218b/m224),
//      unlike the lockstep single-block GEMM where it nulled (m190).
//      Zero numerics/occupancy impact.
// ---------------------------------------------------------------------------

typedef float floatx4 __attribute__((ext_vector_type(4)));
typedef __bf16 bf16x8 __attribute__((ext_vector_type(8)));
typedef unsigned uintx4 __attribute__((ext_vector_type(4)));

#define XHI_OFF 0u
#define XLO_OFF 58720256u           // 32*64*14336 shorts = 58720256 B
#define WHI_OFF 117440512u
#define WLO_OFF 128974848u
#define Y2_OFF  140509184u
#define VP_OFF  0u                  // overlaps xhi: dead once conv2 is done
#define Y2_BYTES 9437184u
#define Y2_FLOATS 2359296           // floats per ks slice = 32*256*36*8

// slab geometry (shorts): iy stride 88, img stride 1760, parity offset 7072
#define SL_IY   88
#define SL_IMG  1760
#define SL_PAR  7072
#define SL_STRIDE 14336             // padded slab stride (28672 B = 28 chunks)

#define TAPSTRIDE 65536             // shorts per tap in w layout

__device__ __forceinline__ void bf16split(float v, short& hs, short& ls) {
  unsigned u = __builtin_bit_cast(unsigned, v);
  unsigned r = (u + 0x7FFFu + ((u >> 16) & 1u)) & 0xFFFF0000u;
  hs = (short)(r >> 16);
  float lo = v - __builtin_bit_cast(float, r);
  unsigned u2 = __builtin_bit_cast(unsigned, lo);
  unsigned r2 = u2 + 0x7FFFu + ((u2 >> 16) & 1u);
  ls = (short)(r2 >> 16);
}

// async 7x1024B wave-linear global->LDS copy (lane gives +16B each)
__device__ __forceinline__ void stage7(const short* gp, short* lp) {
#pragma unroll
  for (int c = 0; c < 7; c++)
    __builtin_amdgcn_global_load_lds(
        (const __attribute__((address_space(1))) void*)(gp + c * 512),
        (__attribute__((address_space(3))) void*)(lp + c * 512), 16, 0, 0);
}

// ============================ conv1: 9x9 s1 + ReLU ==========================
__global__ __launch_bounds__(320) void conv1_k(
    const float* __restrict__ inp, const float* __restrict__ W1,
    const float* __restrict__ b1, short* __restrict__ xhi,
    short* __restrict__ xlo) {
  __shared__ __align__(16) float img[784];
  __shared__ float wl[81 * 34];
  const int blk = blockIdx.x;
  const int b = blk >> 3;
  const int cbase = (blk & 7) * 32;
  const int t = threadIdx.x;

  const float4* src = (const float4*)(inp + b * 784);
  for (int idx = t; idx < 196; idx += 320) ((float4*)img)[idx] = src[idx];
  for (int idx = t; idx < 2592; idx += 320) {
    int c = idx / 81, tap = idx - c * 81;
    wl[tap * 34 + c] = W1[(cbase + c) * 81 + tap];
  }
  __syncthreads();

  const int oy = t >> 4;
  const int ct = t & 15;
  const int c0 = cbase + ct * 2;
  const float bias0 = b1[c0], bias1 = b1[c0 + 1];
  float acc0[20], acc1[20];
#pragma unroll
  for (int ox = 0; ox < 20; ox++) { acc0[ox] = bias0; acc1[ox] = bias1; }

#pragma unroll 1
  for (int i = 0; i < 9; i++) {
    float wr0[9], wr1[9];
#pragma unroll
    for (int j = 0; j < 9; j++) {
      float2 wv = *(const float2*)&wl[(i * 9 + j) * 34 + ct * 2];
      wr0[j] = wv.x; wr1[j] = wv.y;
    }
    float xr[28];
    const float4* rp = (const float4*)&img[(oy + i) * 28];
#pragma unroll
    for (int k = 0; k < 7; k++) {
      float4 v = rp[k];
      xr[4 * k] = v.x; xr[4 * k + 1] = v.y; xr[4 * k + 2] = v.z; xr[4 * k + 3] = v.w;
    }
#pragma unroll
    for (int j = 0; j < 9; j++)
#pragma unroll
      for (int ox = 0; ox < 20; ox++) {
        acc0[ox] = fmaf(xr[ox + j], wr0[j], acc0[ox]);
        acc1[ox] = fmaf(xr[ox + j], wr1[j], acc1[ox]);
      }
  }

  // write directly in conv2's slab layout:
  const int icgG = c0 >> 3;
  const long sbase = ((long)(icgG * 64 + (b >> 2))) * SL_STRIDE
                   + (long)(b & 3) * SL_IMG + (long)oy * SL_IY + (c0 & 7);
#pragma unroll
  for (int ox = 0; ox < 20; ox++) {
    float v0 = fmaxf(acc0[ox], 0.f), v1 = fmaxf(acc1[ox], 0.f);
    short h0, l0, h1, l1;
    bf16split(v0, h0, l0);
    bf16split(v1, h1, l1);
    long a = sbase + (ox & 1) * SL_PAR + (ox >> 1) * 8;
    *(short2*)&xhi[a] = make_short2(h0, h1);
    *(short2*)&xlo[a] = make_short2(l0, l1);
  }
  {
    long a0 = sbase + 80;
    *(short2*)&xhi[a0] = make_short2(0, 0);
    *(short2*)&xlo[a0] = make_short2(0, 0);
    long a1 = sbase + SL_PAR + 80;
    *(short2*)&xhi[a1] = make_short2(0, 0);
    *(short2*)&xlo[a1] = make_short2(0, 0);
  }
}

// ======= W2 transform (coalesced LDS transpose) =============================
__global__ __launch_bounds__(256) void wtrans_k(
    const float* __restrict__ W2, short* __restrict__ whi,
    short* __restrict__ wlo) {
  __shared__ short lh[81 * 258];
  __shared__ short ll[81 * 258];
  const int blk = blockIdx.x;
  const int icg = blk & 31, ocg = blk >> 5;
  const int t = threadIdx.x;

  for (int idx = t; idx < 20736; idx += 256) {
    int c = idx / 648, r = idx - c * 648;      // c = oc_local, r = ics*81+tap
    int ics = r / 81, tap = r - ics * 81;
    float v = W2[(long)(ocg * 32 + c) * 20736 + icg * 648 + r];
    short h, l;
    bf16split(v, h, l);
    lh[tap * 258 + c * 8 + ics] = h;
    ll[tap * 258 + c * 8 + ics] = l;
  }
  __syncthreads();
  const long obase = (long)icg * 2048 + ocg * 256 + t;
#pragma unroll 1
  for (int tap = 0; tap < 88; tap++) {
    short h = 0, l = 0;
    if (tap < 81) { h = lh[tap * 258 + t]; l = ll[tap * 258 + t]; }
    whi[obase + (long)tap * TAPSTRIDE] = h;
    wlo[obase + (long)tap * TAPSTRIDE] = l;
  }
}

// ================= conv2: MFMA bf16-split implicit GEMM =====================
// grid 512: ks = blk&7 == XCD, mb = blk>>3 (4 images). Block M144 x N256;
// 4 waves x (9m,4n). Double-buffered slabs staged via global_load_lds.
// setprio(1) around MFMA clusters (R23). Epilogue: y2p[ks][g][b][s][d].
template <bool SPLIT>
__global__ __launch_bounds__(256, 2) void conv2_k(
    const short* __restrict__ xhi, const short* __restrict__ xlo,
    const short* __restrict__ whi, const short* __restrict__ wlo,
    float* __restrict__ y2) {
  __shared__ __align__(16) short slab[2][SL_STRIDE];   // 2 x 28 KB

  const int blk = blockIdx.x;
  const int ks = blk & 7;
  const int mb = blk >> 3;
  const int t = threadIdx.x;
  const int lane = t & 63;
  const int q = lane >> 4;
  const int ln16 = lane & 15;
  const int wv = t >> 6;

  int combo[9];
#pragma unroll
  for (int mt = 0; mt < 9; mt++) {
    int row = mt * 16 + ln16;
    int im = row / 36;
    int pos = row - im * 36;
    int oy = pos / 6, ox = pos - oy * 6;
    combo[mt] = im * SL_IMG + oy * (2 * SL_IY) + ox * 8;
  }

  floatx4 acc[9][4];
#pragma unroll
  for (int mt = 0; mt < 9; mt++)
#pragma unroll
    for (int nt = 0; nt < 4; nt++) acc[mt][nt] = (floatx4)0.f;

  // per-wave staging offset: 7 chunks of 1024B, lane-linear
  const int stoff = wv * 7 * 512 + lane * 8;

  // prologue: stage hi(icg=0) into slab[0]
  stage7(xhi + (long)(ks * 4 * 64 + mb) * SL_STRIDE + stoff, &slab[0][stoff]);

#pragma unroll 1
  for (int icg = 0; icg < 4; icg++) {
    const int icgG = ks * 4 + icg;
    const long wb0 = ((long)icgG * 256 + wv * 64 + ln16) * 8 + (long)q * TAPSTRIDE;

    __syncthreads();   // drains vmcnt: hi slab ready; all waves done with slab[1]
    // issue lo(icg) -> slab[1], hides under HI compute
    stage7(xlo + (long)(icgG * 64 + mb) * SL_STRIDE + stoff, &slab[1][stoff]);

    // ---------------- HI phase: A_hi * (B_hi + B_lo) ----------------
    {
      bf16x8 cbh[4], cbl[4];
#pragma unroll
      for (int nt = 0; nt < 4; nt++) {
        cbh[nt] = *(const bf16x8*)&whi[wb0 + nt * 128];
        cbl[nt] = *(const bf16x8*)&wlo[wb0 + nt * 128];
      }
      int ip = 0, jp = q;
      int aoff = (jp & 1) * SL_PAR + (jp >> 1) * 8;
      bf16x8 a0 = *(const bf16x8*)&slab[0][aoff + combo[0]];
      bf16x8 a1 = *(const bf16x8*)&slab[0][aoff + combo[1]];
      bf16x8 a2 = *(const bf16x8*)&slab[0][aoff + combo[2]];
#pragma unroll 1
      for (int kst = 0; kst < 21; kst++) {
        const int t0n = (kst < 20) ? (kst + 1) * 4 : 80;
        bf16x8 nbh[4], nbl[4];
#pragma unroll
        for (int nt = 0; nt < 4; nt++) {
          nbh[nt] = *(const bf16x8*)&whi[wb0 + (long)t0n * TAPSTRIDE + nt * 128];
          nbl[nt] = *(const bf16x8*)&wlo[wb0 + (long)t0n * TAPSTRIDE + nt * 128];
        }
        // incremental next-tap (tap += 4, wrap j at 9)
        int jn = jp + 4, in_ = ip;
        if (jn >= 9) { jn -= 9; in_++; }
        const int aoff_n = (jn & 1) * SL_PAR + in_ * SL_IY + (jn >> 1) * 8;
#pragma unroll
        for (int bb = 0; bb < 3; bb++) {
          const int poff = (bb < 2) ? aoff : aoff_n;
          const int cb = (bb < 2) ? (bb + 1) * 3 : 0;
          bf16x8 n0 = *(const bf16x8*)&slab[0][poff + combo[cb + 0]];
          bf16x8 n1 = *(const bf16x8*)&slab[0][poff + combo[cb + 1]];
          bf16x8 n2 = *(const bf16x8*)&slab[0][poff + combo[cb + 2]];
          __builtin_amdgcn_s_setprio(1);
#pragma unroll
          for (int nt = 0; nt < 4; nt++) {
            acc[bb * 3 + 0][nt] = __builtin_amdgcn_mfma_f32_16x16x32_bf16(
                a0, cbh[nt], acc[bb * 3 + 0][nt], 0, 0, 0);
            acc[bb * 3 + 1][nt] = __builtin_amdgcn_mfma_f32_16x16x32_bf16(
                a1, cbh[nt], acc[bb * 3 + 1][nt], 0, 0, 0);
            acc[bb * 3 + 2][nt] = __builtin_amdgcn_mfma_f32_16x16x32_bf16(
                a2, cbh[nt], acc[bb * 3 + 2][nt], 0, 0, 0);
          }
#pragma unroll
          for (int nt = 0; nt < 4; nt++) {
            acc[bb * 3 + 0][nt] = __builtin_amdgcn_mfma_f32_16x16x32_bf16(
                a0, cbl[nt], acc[bb * 3 + 0][nt], 0, 0, 0);
            acc[bb * 3 + 1][nt] = __builtin_amdgcn_mfma_f32_16x16x32_bf16(
                a1, cbl[nt], acc[bb * 3 + 1][nt], 0, 0, 0);
            acc[bb * 3 + 2][nt] = __builtin_amdgcn_mfma_f32_16x16x32_bf16(
                a2, cbl[nt], acc[bb * 3 + 2][nt], 0, 0, 0);
          }
          __builtin_amdgcn_s_setprio(0);
          a0 = n0; a1 = n1; a2 = n2;
        }
#pragma unroll
        for (int nt = 0; nt < 4; nt++) { cbh[nt] = nbh[nt]; cbl[nt] = nbl[nt]; }
        aoff = aoff_n; ip = in_; jp = jn;
      }
    }

    __syncthreads();   // drains vmcnt: lo slab ready; all waves done with slab[0]
    if (icg < 3)       // issue hi(icg+1) -> slab[0], hides under LO compute
      stage7(xhi + (long)((icgG + 1) * 64 + mb) * SL_STRIDE + stoff, &slab[0][stoff]);

    // ---------------- LO phase: A_lo * B_hi ----------------
    {
      bf16x8 cbh[4];
#pragma unroll
      for (int nt = 0; nt < 4; nt++) cbh[nt] = *(const bf16x8*)&whi[wb0 + nt * 128];
      int ip = 0, jp = q;
      int aoff = (jp & 1) * SL_PAR + (jp >> 1) * 8;
      bf16x8 a0 = *(const bf16x8*)&slab[1][aoff + combo[0]];
      bf16x8 a1 = *(const bf16x8*)&slab[1][aoff + combo[1]];
      bf16x8 a2 = *(const bf16x8*)&slab[1][aoff + combo[2]];
#pragma unroll 1
      for (int kst = 0; kst < 21; kst++) {
        const int t0n = (kst < 20) ? (kst + 1) * 4 : 80;
        bf16x8 nbh[4];
#pragma unroll
        for (int nt = 0; nt < 4; nt++)
          nbh[nt] = *(const bf16x8*)&whi[wb0 + (long)t0n * TAPSTRIDE + nt * 128];
        int jn = jp + 4, in_ = ip;
        if (jn >= 9) { jn -= 9; in_++; }
        const int aoff_n = (jn & 1) * SL_PAR + in_ * SL_IY + (jn >> 1) * 8;
#pragma unroll
        for (int bb = 0; bb < 3; bb++) {
          const int poff = (bb < 2) ? aoff : aoff_n;
          const int cb = (bb < 2) ? (bb + 1) * 3 : 0;
          bf16x8 n0 = *(const bf16x8*)&slab[1][poff + combo[cb + 0]];
          bf16x8 n1 = *(const bf16x8*)&slab[1][poff + combo[cb + 1]];
          bf16x8 n2 = *(const bf16x8*)&slab[1][poff + combo[cb + 2]];
          __builtin_amdgcn_s_setprio(1);
#pragma unroll
          for (int nt = 0; nt < 4; nt++) {
            acc[bb * 3 + 0][nt] = __builtin_amdgcn_mfma_f32_16x16x32_bf16(
                a0, cbh[nt], acc[bb * 3 + 0][nt], 0, 0, 0);
            acc[bb * 3 + 1][nt] = __builtin_amdgcn_mfma_f32_16x16x32_bf16(
                a1, cbh[nt], acc[bb * 3 + 1][nt], 0, 0, 0);
            acc[bb * 3 + 2][nt] = __builtin_amdgcn_mfma_f32_16x16x32_bf16(
                a2, cbh[nt], acc[bb * 3 + 2][nt], 0, 0, 0);
          }
          __builtin_amdgcn_s_setprio(0);
          a0 = n0; a1 = n1; a2 = n2;
        }
#pragma unroll
        for (int nt = 0; nt < 4; nt++) cbh[nt] = nbh[nt];
        aoff = aoff_n; ip = in_; jp = jn;
      }
    }
  }

  // epilogue: C/D layout col(n)=lane&15, row(m)=q*4+r.
  // y2p index: ((g*256 + b_img)*36 + s)*8 + d
  {
    float* dst = y2 + (SPLIT ? (long)ks * Y2_FLOATS : 0l);
#pragma unroll
    for (int mt = 0; mt < 9; mt++)
#pragma unroll
      for (int nt = 0; nt < 4; nt++) {
        const int oc = wv * 64 + nt * 16 + ln16;
        const int gg = oc >> 3, dd = oc & 7;
#pragma unroll
        for (int r = 0; r < 4; r++) {
          const int lr = mt * 16 + q * 4 + r;
          const int im = lr / 36;
          const int s = lr - im * 36;
          const long a = ((long)(gg * 256 + mb * 4 + im) * 36 + s) * 8 + dd;
          if (SPLIT) dst[a] = acc[mt][nt][r];
          else       atomicAdd(&dst[a], acc[mt][nt][r]);
        }
      }
  }
}

// ================= primary caps squash + predictions + routing ==============
// R22 structure: 4 waves, 5 blk/CU, thinned barrier chain; bitwise = R19.
template <bool SPLIT>
__global__ __launch_bounds__(256) void caps_k(
    const float* __restrict__ y2, const float* __restrict__ b2,
    const float* __restrict__ Wcaps, const float* __restrict__ b_route,
    float* __restrict__ vpart) {
  __shared__ float u[288];
  __shared__ __align__(16) float up[5760];
  __shared__ float bl[360];
  __shared__ float cl[360];
  __shared__ float sv[160];
  __shared__ float scale[10];
  const int blk = blockIdx.x;
  const int g = blk & 31, b = blk >> 5;
  const int t = threadIdx.x;

  // u-load: y2p[ks][g][b][s][d] -> 288 contiguous floats per slice (coalesced)
  {
    const long base = ((long)g * 256 + b) * 288;
    for (int idx = t; idx < 288; idx += 256) {
      float a;
      if (SPLIT) {
        a = 0.f;
#pragma unroll
        for (int ks = 0; ks < 8; ks++) a += y2[(long)ks * Y2_FLOATS + base + idx];
      } else {
        a = y2[base + idx];
      }
      u[idx] = a + b2[g * 8 + (idx & 7)];
    }
  }
  for (int idx = t; idx < 360; idx += 256) bl[idx] = b_route[g * 360 + idx];
  __syncthreads();
  // squash: thread t<36 owns row t -> compute usc in-register, scale row
  if (t < 36) {
    float l2 = 0.f;
#pragma unroll
    for (int d = 0; d < 8; d++) { float v = u[t * 8 + d]; l2 = fmaf(v, v, l2); }
    float l = sqrtf(l2);
    const float us = (l2 / (1.f + l2)) / (l + 1e-8f);
#pragma unroll
    for (int d = 0; d < 8; d++) u[t * 8 + d] *= us;
  }
  __syncthreads();
  // up einsum, float4 over k (bit-identical order over d per component)
  for (int idx = t; idx < 1440; idx += 256) {
    int s = idx / 40, k4 = idx - s * 40;
    const float4* wp4 = (const float4*)(Wcaps + (long)(g * 36 + s) * 1280) + k4;
    float4 a = make_float4(0.f, 0.f, 0.f, 0.f);
#pragma unroll
    for (int d = 0; d < 8; d++) {
      float uv = u[s * 8 + d];
      float4 w = wp4[d * 40];
      a.x = fmaf(uv, w.x, a.x); a.y = fmaf(uv, w.y, a.y);
      a.z = fmaf(uv, w.z, a.z); a.w = fmaf(uv, w.w, a.w);
    }
    ((float4*)up)[idx] = a;
  }
  __syncthreads();

  for (int r = 0; r < 3; r++) {
    if (t < 36) {
      float m = bl[t * 10];
#pragma unroll
      for (int oc = 1; oc < 10; oc++) m = fmaxf(m, bl[t * 10 + oc]);
      float e[10]; float sum = 0.f;
#pragma unroll
      for (int oc = 0; oc < 10; oc++) { e[oc] = expf(bl[t * 10 + oc] - m); sum += e[oc]; }
      float inv = 1.f / sum;
#pragma unroll
      for (int oc = 0; oc < 10; oc++) cl[t * 10 + oc] = e[oc] * inv;
    }
    __syncthreads();
    if (t < 160) {
      const int oc = t >> 4;
      float a = 0.f;
#pragma unroll 1
      for (int s = 0; s < 36; s++) a = fmaf(cl[s * 10 + oc], up[s * 160 + t], a);
      sv[t] = a;
    }
    __syncthreads();
    if (t < 10) {
      float l2 = 0.f;
#pragma unroll
      for (int od = 0; od < 16; od++) { float v = sv[t * 16 + od]; l2 = fmaf(v, v, l2); }
      scale[t] = (l2 / (1.f + l2)) / (sqrtf(l2) + 1e-8f);
    }
    __syncthreads();
    if (r < 2) {
      for (int idx = t; idx < 360; idx += 256) {
        int s = idx / 10, oc = idx - s * 10;
        const float sc = scale[oc];
        float a = 0.f;
#pragma unroll
        for (int od = 0; od < 16; od++)
          a = fmaf(up[s * 160 + oc * 16 + od], sv[oc * 16 + od] * sc, a);
        bl[idx] += a;
      }
      __syncthreads();
    }
  }
  if (t < 160) vpart[(b * 32 + g) * 160 + t] = sv[t] * scale[t >> 4];
}

// ================== final: sum over groups + probs ==========================
__global__ __launch_bounds__(192) void final_k(
    const float* __restrict__ vpart, float* __restrict__ out) {
  __shared__ float v[160];
  const int b = blockIdx.x, t = threadIdx.x;
  if (t < 160) {
    float a = 0.f;
#pragma unroll 4
    for (int g = 0; g < 32; g++) a += vpart[(b * 32 + g) * 160 + t];
    v[t] = a;
    out[b * 160 + t] = a;
  }
  __syncthreads();
  if (t < 10) {
    float l2 = 0.f;
#pragma unroll
    for (int od = 0; od < 16; od++) { float x = v[t * 16 + od]; l2 = fmaf(x, x, l2); }
    out[40960 + b * 10 + t] = sqrtf(l2);
  }
}

// ===========================================================================
extern "C" void kernel_launch(void* const* d_in, const int* in_sizes, int n_in,
                              void* d_out, int out_size, void* d_ws, size_t ws_size,
                              hipStream_t stream) {
  const float* inp     = (const float*)d_in[0];
  const float* W1      = (const float*)d_in[1];
  const float* b1      = (const float*)d_in[2];
  const float* W2      = (const float*)d_in[3];
  const float* b2      = (const float*)d_in[4];
  const float* Wcaps   = (const float*)d_in[5];
  const float* b_route = (const float*)d_in[6];
  float* out = (float*)d_out;
  char* ws = (char*)d_ws;

  short* xhi = (short*)(ws + XHI_OFF);
  short* xlo = (short*)(ws + XLO_OFF);
  short* whi = (short*)(ws + WHI_OFF);
  short* wlo = (short*)(ws + WLO_OFF);
  float* y2  = (float*)(ws + Y2_OFF);
  float* vp  = (float*)(ws + VP_OFF);   // overlaps xhi (dead after conv2)

  const bool split = ws_size >= (size_t)Y2_OFF + 8ull * Y2_BYTES;

  conv1_k <<<2048, 320, 0, stream>>>(inp, W1, b1, xhi, xlo);
  wtrans_k<<<256, 256, 0, stream>>>(W2, whi, wlo);
  if (split) {
    conv2_k<true> <<<512, 256, 0, stream>>>(xhi, xlo, whi, wlo, y2);
    caps_k<true>  <<<8192, 256, 0, stream>>>(y2, b2, Wcaps, b_route, vp);
  } else {
    (void)hipMemsetAsync(y2, 0, Y2_BYTES, stream);
    conv2_k<false> <<<512, 256, 0, stream>>>(xhi, xlo, whi, wlo, y2);
    caps_k<false>  <<<8192, 256, 0, stream>>>(y2, b2, Wcaps, b_route, vp);
  }
  final_k <<<256, 192, 0, stream>>>(vp, out);
}

// Round 13
// 481.456 us; speedup vs baseline: 1.0685x; 1.0685x over previous
//
#include <hip/hip_runtime.h>
#include <math.h>

// ---------------------------------------------------------------------------
// CapsNet forward on MI355X.
// R24: final revert to R22 (best measured 486-488us). R23's setprio around
//      MFMA clusters regressed via register pressure: VGPR 124->128 and
//      +32MB WRITE / +22MB FETCH of scratch-spill traffic (setprio pairs
//      fence the scheduler, stretching prefetch live ranges). Session
//      summary: wins = slab-layout+global_load_lds staging (R13), split-K
//      plain-store epilogue + coalesced [ks][g][b][s][d] partials (R18/19);
//      falsified = 32x32x16 (2x), caps fusion/wave0/2-img, conv2 setprio.
// ---------------------------------------------------------------------------

typedef float floatx4 __attribute__((ext_vector_type(4)));
typedef __bf16 bf16x8 __attribute__((ext_vector_type(8)));
typedef unsigned uintx4 __attribute__((ext_vector_type(4)));

#define XHI_OFF 0u
#define XLO_OFF 58720256u           // 32*64*14336 shorts = 58720256 B
#define WHI_OFF 117440512u
#define WLO_OFF 128974848u
#define Y2_OFF  140509184u
#define VP_OFF  0u                  // overlaps xhi: dead once conv2 is done
#define Y2_BYTES 9437184u
#define Y2_FLOATS 2359296           // floats per ks slice = 32*256*36*8

// slab geometry (shorts): iy stride 88, img stride 1760, parity offset 7072
#define SL_IY   88
#define SL_IMG  1760
#define SL_PAR  7072
#define SL_STRIDE 14336             // padded slab stride (28672 B = 28 chunks)

#define TAPSTRIDE 65536             // shorts per tap in w layout

__device__ __forceinline__ void bf16split(float v, short& hs, short& ls) {
  unsigned u = __builtin_bit_cast(unsigned, v);
  unsigned r = (u + 0x7FFFu + ((u >> 16) & 1u)) & 0xFFFF0000u;
  hs = (short)(r >> 16);
  float lo = v - __builtin_bit_cast(float, r);
  unsigned u2 = __builtin_bit_cast(unsigned, lo);
  unsigned r2 = u2 + 0x7FFFu + ((u2 >> 16) & 1u);
  ls = (short)(r2 >> 16);
}

// async 7x1024B wave-linear global->LDS copy (lane gives +16B each)
__device__ __forceinline__ void stage7(const short* gp, short* lp) {
#pragma unroll
  for (int c = 0; c < 7; c++)
    __builtin_amdgcn_global_load_lds(
        (const __attribute__((address_space(1))) void*)(gp + c * 512),
        (__attribute__((address_space(3))) void*)(lp + c * 512), 16, 0, 0);
}

// ============================ conv1: 9x9 s1 + ReLU ==========================
__global__ __launch_bounds__(320) void conv1_k(
    const float* __restrict__ inp, const float* __restrict__ W1,
    const float* __restrict__ b1, short* __restrict__ xhi,
    short* __restrict__ xlo) {
  __shared__ __align__(16) float img[784];
  __shared__ float wl[81 * 34];
  const int blk = blockIdx.x;
  const int b = blk >> 3;
  const int cbase = (blk & 7) * 32;
  const int t = threadIdx.x;

  const float4* src = (const float4*)(inp + b * 784);
  for (int idx = t; idx < 196; idx += 320) ((float4*)img)[idx] = src[idx];
  for (int idx = t; idx < 2592; idx += 320) {
    int c = idx / 81, tap = idx - c * 81;
    wl[tap * 34 + c] = W1[(cbase + c) * 81 + tap];
  }
  __syncthreads();

  const int oy = t >> 4;
  const int ct = t & 15;
  const int c0 = cbase + ct * 2;
  const float bias0 = b1[c0], bias1 = b1[c0 + 1];
  float acc0[20], acc1[20];
#pragma unroll
  for (int ox = 0; ox < 20; ox++) { acc0[ox] = bias0; acc1[ox] = bias1; }

#pragma unroll 1
  for (int i = 0; i < 9; i++) {
    float wr0[9], wr1[9];
#pragma unroll
    for (int j = 0; j < 9; j++) {
      float2 wv = *(const float2*)&wl[(i * 9 + j) * 34 + ct * 2];
      wr0[j] = wv.x; wr1[j] = wv.y;
    }
    float xr[28];
    const float4* rp = (const float4*)&img[(oy + i) * 28];
#pragma unroll
    for (int k = 0; k < 7; k++) {
      float4 v = rp[k];
      xr[4 * k] = v.x; xr[4 * k + 1] = v.y; xr[4 * k + 2] = v.z; xr[4 * k + 3] = v.w;
    }
#pragma unroll
    for (int j = 0; j < 9; j++)
#pragma unroll
      for (int ox = 0; ox < 20; ox++) {
        acc0[ox] = fmaf(xr[ox + j], wr0[j], acc0[ox]);
        acc1[ox] = fmaf(xr[ox + j], wr1[j], acc1[ox]);
      }
  }

  // write directly in conv2's slab layout:
  const int icgG = c0 >> 3;
  const long sbase = ((long)(icgG * 64 + (b >> 2))) * SL_STRIDE
                   + (long)(b & 3) * SL_IMG + (long)oy * SL_IY + (c0 & 7);
#pragma unroll
  for (int ox = 0; ox < 20; ox++) {
    float v0 = fmaxf(acc0[ox], 0.f), v1 = fmaxf(acc1[ox], 0.f);
    short h0, l0, h1, l1;
    bf16split(v0, h0, l0);
    bf16split(v1, h1, l1);
    long a = sbase + (ox & 1) * SL_PAR + (ox >> 1) * 8;
    *(short2*)&xhi[a] = make_short2(h0, h1);
    *(short2*)&xlo[a] = make_short2(l0, l1);
  }
  {
    long a0 = sbase + 80;
    *(short2*)&xhi[a0] = make_short2(0, 0);
    *(short2*)&xlo[a0] = make_short2(0, 0);
    long a1 = sbase + SL_PAR + 80;
    *(short2*)&xhi[a1] = make_short2(0, 0);
    *(short2*)&xlo[a1] = make_short2(0, 0);
  }
}

// ======= W2 transform (coalesced LDS transpose) =============================
__global__ __launch_bounds__(256) void wtrans_k(
    const float* __restrict__ W2, short* __restrict__ whi,
    short* __restrict__ wlo) {
  __shared__ short lh[81 * 258];
  __shared__ short ll[81 * 258];
  const int blk = blockIdx.x;
  const int icg = blk & 31, ocg = blk >> 5;
  const int t = threadIdx.x;

  for (int idx = t; idx < 20736; idx += 256) {
    int c = idx / 648, r = idx - c * 648;      // c = oc_local, r = ics*81+tap
    int ics = r / 81, tap = r - ics * 81;
    float v = W2[(long)(ocg * 32 + c) * 20736 + icg * 648 + r];
    short h, l;
    bf16split(v, h, l);
    lh[tap * 258 + c * 8 + ics] = h;
    ll[tap * 258 + c * 8 + ics] = l;
  }
  __syncthreads();
  const long obase = (long)icg * 2048 + ocg * 256 + t;
#pragma unroll 1
  for (int tap = 0; tap < 88; tap++) {
    short h = 0, l = 0;
    if (tap < 81) { h = lh[tap * 258 + t]; l = ll[tap * 258 + t]; }
    whi[obase + (long)tap * TAPSTRIDE] = h;
    wlo[obase + (long)tap * TAPSTRIDE] = l;
  }
}

// ================= conv2: MFMA bf16-split implicit GEMM =====================
// grid 512: ks = blk&7 == XCD, mb = blk>>3 (4 images). Block M144 x N256;
// 4 waves x (9m,4n). Double-buffered slabs staged via global_load_lds.
// Epilogue writes y2p[ks][g][b][s][d] (SPLIT: plain store; else atomicAdd).
template <bool SPLIT>
__global__ __launch_bounds__(256, 2) void conv2_k(
    const short* __restrict__ xhi, const short* __restrict__ xlo,
    const short* __restrict__ whi, const short* __restrict__ wlo,
    float* __restrict__ y2) {
  __shared__ __align__(16) short slab[2][SL_STRIDE];   // 2 x 28 KB

  const int blk = blockIdx.x;
  const int ks = blk & 7;
  const int mb = blk >> 3;
  const int t = threadIdx.x;
  const int lane = t & 63;
  const int q = lane >> 4;
  const int ln16 = lane & 15;
  const int wv = t >> 6;

  int combo[9];
#pragma unroll
  for (int mt = 0; mt < 9; mt++) {
    int row = mt * 16 + ln16;
    int im = row / 36;
    int pos = row - im * 36;
    int oy = pos / 6, ox = pos - oy * 6;
    combo[mt] = im * SL_IMG + oy * (2 * SL_IY) + ox * 8;
  }

  floatx4 acc[9][4];
#pragma unroll
  for (int mt = 0; mt < 9; mt++)
#pragma unroll
    for (int nt = 0; nt < 4; nt++) acc[mt][nt] = (floatx4)0.f;

  // per-wave staging offset: 7 chunks of 1024B, lane-linear
  const int stoff = wv * 7 * 512 + lane * 8;

  // prologue: stage hi(icg=0) into slab[0]
  stage7(xhi + (long)(ks * 4 * 64 + mb) * SL_STRIDE + stoff, &slab[0][stoff]);

#pragma unroll 1
  for (int icg = 0; icg < 4; icg++) {
    const int icgG = ks * 4 + icg;
    const long wb0 = ((long)icgG * 256 + wv * 64 + ln16) * 8 + (long)q * TAPSTRIDE;

    __syncthreads();   // drains vmcnt: hi slab ready; all waves done with slab[1]
    // issue lo(icg) -> slab[1], hides under HI compute
    stage7(xlo + (long)(icgG * 64 + mb) * SL_STRIDE + stoff, &slab[1][stoff]);

    // ---------------- HI phase: A_hi * (B_hi + B_lo) ----------------
    {
      bf16x8 cbh[4], cbl[4];
#pragma unroll
      for (int nt = 0; nt < 4; nt++) {
        cbh[nt] = *(const bf16x8*)&whi[wb0 + nt * 128];
        cbl[nt] = *(const bf16x8*)&wlo[wb0 + nt * 128];
      }
      int ip = 0, jp = q;
      int aoff = (jp & 1) * SL_PAR + (jp >> 1) * 8;
      bf16x8 a0 = *(const bf16x8*)&slab[0][aoff + combo[0]];
      bf16x8 a1 = *(const bf16x8*)&slab[0][aoff + combo[1]];
      bf16x8 a2 = *(const bf16x8*)&slab[0][aoff + combo[2]];
#pragma unroll 1
      for (int kst = 0; kst < 21; kst++) {
        const int t0n = (kst < 20) ? (kst + 1) * 4 : 80;
        bf16x8 nbh[4], nbl[4];
#pragma unroll
        for (int nt = 0; nt < 4; nt++) {
          nbh[nt] = *(const bf16x8*)&whi[wb0 + (long)t0n * TAPSTRIDE + nt * 128];
          nbl[nt] = *(const bf16x8*)&wlo[wb0 + (long)t0n * TAPSTRIDE + nt * 128];
        }
        // incremental next-tap (tap += 4, wrap j at 9)
        int jn = jp + 4, in_ = ip;
        if (jn >= 9) { jn -= 9; in_++; }
        const int aoff_n = (jn & 1) * SL_PAR + in_ * SL_IY + (jn >> 1) * 8;
#pragma unroll
        for (int bb = 0; bb < 3; bb++) {
          const int poff = (bb < 2) ? aoff : aoff_n;
          const int cb = (bb < 2) ? (bb + 1) * 3 : 0;
          bf16x8 n0 = *(const bf16x8*)&slab[0][poff + combo[cb + 0]];
          bf16x8 n1 = *(const bf16x8*)&slab[0][poff + combo[cb + 1]];
          bf16x8 n2 = *(const bf16x8*)&slab[0][poff + combo[cb + 2]];
#pragma unroll
          for (int nt = 0; nt < 4; nt++) {
            acc[bb * 3 + 0][nt] = __builtin_amdgcn_mfma_f32_16x16x32_bf16(
                a0, cbh[nt], acc[bb * 3 + 0][nt], 0, 0, 0);
            acc[bb * 3 + 1][nt] = __builtin_amdgcn_mfma_f32_16x16x32_bf16(
                a1, cbh[nt], acc[bb * 3 + 1][nt], 0, 0, 0);
            acc[bb * 3 + 2][nt] = __builtin_amdgcn_mfma_f32_16x16x32_bf16(
                a2, cbh[nt], acc[bb * 3 + 2][nt], 0, 0, 0);
          }
#pragma unroll
          for (int nt = 0; nt < 4; nt++) {
            acc[bb * 3 + 0][nt] = __builtin_amdgcn_mfma_f32_16x16x32_bf16(
                a0, cbl[nt], acc[bb * 3 + 0][nt], 0, 0, 0);
            acc[bb * 3 + 1][nt] = __builtin_amdgcn_mfma_f32_16x16x32_bf16(
                a1, cbl[nt], acc[bb * 3 + 1][nt], 0, 0, 0);
            acc[bb * 3 + 2][nt] = __builtin_amdgcn_mfma_f32_16x16x32_bf16(
                a2, cbl[nt], acc[bb * 3 + 2][nt], 0, 0, 0);
          }
          a0 = n0; a1 = n1; a2 = n2;
        }
#pragma unroll
        for (int nt = 0; nt < 4; nt++) { cbh[nt] = nbh[nt]; cbl[nt] = nbl[nt]; }
        aoff = aoff_n; ip = in_; jp = jn;
      }
    }

    __syncthreads();   // drains vmcnt: lo slab ready; all waves done with slab[0]
    if (icg < 3)       // issue hi(icg+1) -> slab[0], hides under LO compute
      stage7(xhi + (long)((icgG + 1) * 64 + mb) * SL_STRIDE + stoff, &slab[0][stoff]);

    // ---------------- LO phase: A_lo * B_hi ----------------
    {
      bf16x8 cbh[4];
#pragma unroll
      for (int nt = 0; nt < 4; nt++) cbh[nt] = *(const bf16x8*)&whi[wb0 + nt * 128];
      int ip = 0, jp = q;
      int aoff = (jp & 1) * SL_PAR + (jp >> 1) * 8;
      bf16x8 a0 = *(const bf16x8*)&slab[1][aoff + combo[0]];
      bf16x8 a1 = *(const bf16x8*)&slab[1][aoff + combo[1]];
      bf16x8 a2 = *(const bf16x8*)&slab[1][aoff + combo[2]];
#pragma unroll 1
      for (int kst = 0; kst < 21; kst++) {
        const int t0n = (kst < 20) ? (kst + 1) * 4 : 80;
        bf16x8 nbh[4];
#pragma unroll
        for (int nt = 0; nt < 4; nt++)
          nbh[nt] = *(const bf16x8*)&whi[wb0 + (long)t0n * TAPSTRIDE + nt * 128];
        int jn = jp + 4, in_ = ip;
        if (jn >= 9) { jn -= 9; in_++; }
        const int aoff_n = (jn & 1) * SL_PAR + in_ * SL_IY + (jn >> 1) * 8;
#pragma unroll
        for (int bb = 0; bb < 3; bb++) {
          const int poff = (bb < 2) ? aoff : aoff_n;
          const int cb = (bb < 2) ? (bb + 1) * 3 : 0;
          bf16x8 n0 = *(const bf16x8*)&slab[1][poff + combo[cb + 0]];
          bf16x8 n1 = *(const bf16x8*)&slab[1][poff + combo[cb + 1]];
          bf16x8 n2 = *(const bf16x8*)&slab[1][poff + combo[cb + 2]];
#pragma unroll
          for (int nt = 0; nt < 4; nt++) {
            acc[bb * 3 + 0][nt] = __builtin_amdgcn_mfma_f32_16x16x32_bf16(
                a0, cbh[nt], acc[bb * 3 + 0][nt], 0, 0, 0);
            acc[bb * 3 + 1][nt] = __builtin_amdgcn_mfma_f32_16x16x32_bf16(
                a1, cbh[nt], acc[bb * 3 + 1][nt], 0, 0, 0);
            acc[bb * 3 + 2][nt] = __builtin_amdgcn_mfma_f32_16x16x32_bf16(
                a2, cbh[nt], acc[bb * 3 + 2][nt], 0, 0, 0);
          }
          a0 = n0; a1 = n1; a2 = n2;
        }
#pragma unroll
        for (int nt = 0; nt < 4; nt++) cbh[nt] = nbh[nt];
        aoff = aoff_n; ip = in_; jp = jn;
      }
    }
  }

  // epilogue: C/D layout col(n)=lane&15, row(m)=q*4+r.
  // y2p index: ((g*256 + b_img)*36 + s)*8 + d
  {
    float* dst = y2 + (SPLIT ? (long)ks * Y2_FLOATS : 0l);
#pragma unroll
    for (int mt = 0; mt < 9; mt++)
#pragma unroll
      for (int nt = 0; nt < 4; nt++) {
        const int oc = wv * 64 + nt * 16 + ln16;
        const int gg = oc >> 3, dd = oc & 7;
#pragma unroll
        for (int r = 0; r < 4; r++) {
          const int lr = mt * 16 + q * 4 + r;
          const int im = lr / 36;
          const int s = lr - im * 36;
          const long a = ((long)(gg * 256 + mb * 4 + im) * 36 + s) * 8 + dd;
          if (SPLIT) dst[a] = acc[mt][nt][r];
          else       atomicAdd(&dst[a], acc[mt][nt][r]);
        }
      }
  }
}

// ================= primary caps squash + predictions + routing ==============
// R22 structure: 4 waves, 5 blk/CU, thinned barrier chain; bitwise = R19.
template <bool SPLIT>
__global__ __launch_bounds__(256) void caps_k(
    const float* __restrict__ y2, const float* __restrict__ b2,
    const float* __restrict__ Wcaps, const float* __restrict__ b_route,
    float* __restrict__ vpart) {
  __shared__ float u[288];
  __shared__ __align__(16) float up[5760];
  __shared__ float bl[360];
  __shared__ float cl[360];
  __shared__ float sv[160];
  __shared__ float scale[10];
  const int blk = blockIdx.x;
  const int g = blk & 31, b = blk >> 5;
  const int t = threadIdx.x;

  // u-load: y2p[ks][g][b][s][d] -> 288 contiguous floats per slice (coalesced)
  {
    const long base = ((long)g * 256 + b) * 288;
    for (int idx = t; idx < 288; idx += 256) {
      float a;
      if (SPLIT) {
        a = 0.f;
#pragma unroll
        for (int ks = 0; ks < 8; ks++) a += y2[(long)ks * Y2_FLOATS + base + idx];
      } else {
        a = y2[base + idx];
      }
      u[idx] = a + b2[g * 8 + (idx & 7)];
    }
  }
  for (int idx = t; idx < 360; idx += 256) bl[idx] = b_route[g * 360 + idx];
  __syncthreads();
  // squash: thread t<36 owns row t -> compute usc in-register, scale row
  if (t < 36) {
    float l2 = 0.f;
#pragma unroll
    for (int d = 0; d < 8; d++) { float v = u[t * 8 + d]; l2 = fmaf(v, v, l2); }
    float l = sqrtf(l2);
    const float us = (l2 / (1.f + l2)) / (l + 1e-8f);
#pragma unroll
    for (int d = 0; d < 8; d++) u[t * 8 + d] *= us;
  }
  __syncthreads();
  // up einsum, float4 over k (bit-identical order over d per component)
  for (int idx = t; idx < 1440; idx += 256) {
    int s = idx / 40, k4 = idx - s * 40;
    const float4* wp4 = (const float4*)(Wcaps + (long)(g * 36 + s) * 1280) + k4;
    float4 a = make_float4(0.f, 0.f, 0.f, 0.f);
#pragma unroll
    for (int d = 0; d < 8; d++) {
      float uv = u[s * 8 + d];
      float4 w = wp4[d * 40];
      a.x = fmaf(uv, w.x, a.x); a.y = fmaf(uv, w.y, a.y);
      a.z = fmaf(uv, w.z, a.z); a.w = fmaf(uv, w.w, a.w);
    }
    ((float4*)up)[idx] = a;
  }
  __syncthreads();

  for (int r = 0; r < 3; r++) {
    if (t < 36) {
      float m = bl[t * 10];
#pragma unroll
      for (int oc = 1; oc < 10; oc++) m = fmaxf(m, bl[t * 10 + oc]);
      float e[10]; float sum = 0.f;
#pragma unroll
      for (int oc = 0; oc < 10; oc++) { e[oc] = expf(bl[t * 10 + oc] - m); sum += e[oc]; }
      float inv = 1.f / sum;
#pragma unroll
      for (int oc = 0; oc < 10; oc++) cl[t * 10 + oc] = e[oc] * inv;
    }
    __syncthreads();
    if (t < 160) {
      const int oc = t >> 4;
      float a = 0.f;
#pragma unroll 1
      for (int s = 0; s < 36; s++) a = fmaf(cl[s * 10 + oc], up[s * 160 + t], a);
      sv[t] = a;
    }
    __syncthreads();
    if (t < 10) {
      float l2 = 0.f;
#pragma unroll
      for (int od = 0; od < 16; od++) { float v = sv[t * 16 + od]; l2 = fmaf(v, v, l2); }
      scale[t] = (l2 / (1.f + l2)) / (sqrtf(l2) + 1e-8f);
    }
    __syncthreads();
    if (r < 2) {
      for (int idx = t; idx < 360; idx += 256) {
        int s = idx / 10, oc = idx - s * 10;
        const float sc = scale[oc];
        float a = 0.f;
#pragma unroll
        for (int od = 0; od < 16; od++)
          a = fmaf(up[s * 160 + oc * 16 + od], sv[oc * 16 + od] * sc, a);
        bl[idx] += a;
      }
      __syncthreads();
    }
  }
  if (t < 160) vpart[(b * 32 + g) * 160 + t] = sv[t] * scale[t >> 4];
}

// ================== final: sum over groups + probs ==========================
__global__ __launch_bounds__(192) void final_k(
    const float* __restrict__ vpart, float* __restrict__ out) {
  __shared__ float v[160];
  const int b = blockIdx.x, t = threadIdx.x;
  if (t < 160) {
    float a = 0.f;
#pragma unroll 4
    for (int g = 0; g < 32; g++) a += vpart[(b * 32 + g) * 160 + t];
    v[t] = a;
    out[b * 160 + t] = a;
  }
  __syncthreads();
  if (t < 10) {
    float l2 = 0.f;
#pragma unroll
    for (int od = 0; od < 16; od++) { float x = v[t * 16 + od]; l2 = fmaf(x, x, l2); }
    out[40960 + b * 10 + t] = sqrtf(l2);
  }
}

// ===========================================================================
extern "C" void kernel_launch(void* const* d_in, const int* in_sizes, int n_in,
                              void* d_out, int out_size, void* d_ws, size_t ws_size,
                              hipStream_t stream) {
  const float* inp     = (const float*)d_in[0];
  const float* W1      = (const float*)d_in[1];
  const float* b1      = (const float*)d_in[2];
  const float* W2      = (const float*)d_in[3];
  const float* b2      = (const float*)d_in[4];
  const float* Wcaps   = (const float*)d_in[5];
  const float* b_route = (const float*)d_in[6];
  float* out = (float*)d_out;
  char* ws = (char*)d_ws;

  short* xhi = (short*)(ws + XHI_OFF);
  short* xlo = (short*)(ws + XLO_OFF);
  short* whi = (short*)(ws + WHI_OFF);
  short* wlo = (short*)(ws + WLO_OFF);
  float* y2  = (float*)(ws + Y2_OFF);
  float* vp  = (float*)(ws + VP_OFF);   // overlaps xhi (dead after conv2)

  const bool split = ws_size >= (size_t)Y2_OFF + 8ull * Y2_BYTES;

  conv1_k <<<2048, 320, 0, stream>>>(inp, W1, b1, xhi, xlo);
  wtrans_k<<<256, 256, 0, stream>>>(W2, whi, wlo);
  if (split) {
    conv2_k<true> <<<512, 256, 0, stream>>>(xhi, xlo, whi, wlo, y2);
    caps_k<true>  <<<8192, 256, 0, stream>>>(y2, b2, Wcaps, b_route, vp);
  } else {
    (void)hipMemsetAsync(y2, 0, Y2_BYTES, stream);
    conv2_k<false> <<<512, 256, 0, stream>>>(xhi, xlo, whi, wlo, y2);
    caps_k<false>  <<<8192, 256, 0, stream>>>(y2, b2, Wcaps, b_route, vp);
  }
  final_k <<<256, 192, 0, stream>>>(vp, out);
}